// Round 5
// baseline (79.199 us; speedup 1.0000x reference)
//
#include <hip/hip_runtime.h>

typedef _Float16 half8 __attribute__((ext_vector_type(8)));
typedef float    f32x4 __attribute__((ext_vector_type(4)));

#define NLEN   8388608
#define KTAPS  257
#define MPAD   256
#define OUTLEN (NLEN + MPAD)        /* 8388864 = 2049*4096 */
#define TPB    256
#define BT     4096                 /* complex outputs per block */
#define NBLK   ((OUTLEN + BT - 1) / BT)   /* 2049 */
#define NCH    9                    /* K chunks of 32 -> GEMM-K = 288 */
#define XELEM  (BT + 288)           /* staged elems per component: 4384 */
#define XSLOT  (XELEM / 8)          /* 548 16B slots */
#define XPAD   556                  /* + swizzle margin */
#define AFSLOT (2 * NCH * 64)       /* 1152 half8 slots = 18432 B */

__device__ __forceinline__ int swz(int t) { return t ^ ((t >> 3) & 7); }

/* ---------- shared staging helper (identical math to R3) ---------- */
__device__ __forceinline__ void stage_x(const float* __restrict__ xr,
                                        const float* __restrict__ xi,
                                        half8 (*lx)[XPAD], int xbase, int tid)
{
    const bool interior = (xbase >= 0) && (xbase + 8 * XSLOT <= NLEN);
    if (interior) {
        for (int T = tid; T < XSLOT; T += TPB) {
            const int g = xbase + 8 * T;
            const f32x4 a0 = *(const f32x4*)(xr + g);
            const f32x4 a1 = *(const f32x4*)(xr + g + 4);
            const f32x4 b0 = *(const f32x4*)(xi + g);
            const f32x4 b1 = *(const f32x4*)(xi + g + 4);
            half8 vr, vi;
            #pragma unroll
            for (int e = 0; e < 4; ++e) {
                vr[e]     = (_Float16)a0[e];
                vr[e + 4] = (_Float16)a1[e];
                vi[e]     = (_Float16)b0[e];
                vi[e + 4] = (_Float16)b1[e];
            }
            const int Ts = swz(T);
            lx[0][Ts] = vr;
            lx[1][Ts] = vi;
        }
    } else {
        for (int T = tid; T < XSLOT; T += TPB) {
            const int g = xbase + 8 * T;
            half8 vr, vi;
            #pragma unroll
            for (int e = 0; e < 8; ++e) {
                const int ge = g + e;
                const bool ok = (ge >= 0) && (ge < NLEN);
                vr[e] = (_Float16)(ok ? xr[ge] : 0.0f);
                vi[e] = (_Float16)(ok ? xi[ge] : 0.0f);
            }
            const int Ts = swz(T);
            lx[0][Ts] = vr;
            lx[1][Ts] = vi;
        }
    }
}

/* ---------- pre-kernel: build weight-fragment table in global ws ---------- */
__global__ __launch_bounds__(TPB) void build_af(
    const float* __restrict__ wr, const float* __restrict__ wi,
    half8* __restrict__ af)
{
    for (int i = threadIdx.x; i < AFSLOT; i += TPB) {
        const int comp = i / (NCH * 64);
        const int rem  = i % (NCH * 64);
        const int c    = rem >> 6;
        const int l    = rem & 63;
        const int row  = l & 15;
        const int jb   = 32 * c + 8 * (l >> 4);
        const float* wp = comp ? wi : wr;
        half8 v;
        #pragma unroll
        for (int e = 0; e < 8; ++e) {
            const int k = jb + e - row;
            const float f = (k >= 0 && k < KTAPS) ? wp[k] : 0.0f;
            v[e] = (_Float16)f;
        }
        af[i] = v;
    }
}

/* ---------- main kernel, weight frags from global ws (8 blocks/CU) ---------- */
__global__ __launch_bounds__(TPB, 8) void cconv_ws(
    const float* __restrict__ xr, const float* __restrict__ xi,
    const half8* __restrict__ af, float* __restrict__ out)
{
    __shared__ half8 lx[2][XPAD];

    const int tid   = threadIdx.x;
    const int wv    = tid >> 6;
    const int lane  = tid & 63;
    const int n15   = lane & 15;
    const int lg    = lane >> 4;
    const int t0    = blockIdx.x * BT;
    const int xbase = t0 - MPAD;

    stage_x(xr, xi, lx, xbase, tid);
    __syncthreads();

    f32x4 accr[4], acci[4];
    #pragma unroll
    for (int t = 0; t < 4; ++t) { accr[t] = (f32x4)0.0f; acci[t] = (f32x4)0.0f; }

    const int sT0 = 128 * wv + 2 * n15 + lg;
    const half8* afr = af + lane;              /* comp 0, chunk c at +64*c  */
    const half8* afi = af + NCH * 64 + lane;   /* comp 1                     */

    half8 awr = afr[0];
    half8 awi = afi[0];
    for (int c = 0; c < NCH; ++c) {
        const int cn = (c + 1 < NCH) ? c + 1 : 0;     /* harmless reload on last */
        const half8 nwr = afr[cn * 64];
        const half8 nwi = afi[cn * 64];
        const half8 awin = -awi;                      /* exact fp16 sign flip */
        #pragma unroll
        for (int t = 0; t < 4; ++t) {
            const int Ts = swz(sT0 + 32 * t + 4 * c);
            const half8 br = lx[0][Ts];
            const half8 bi = lx[1][Ts];
            accr[t] = __builtin_amdgcn_mfma_f32_16x16x32_f16(awr,  br, accr[t], 0, 0, 0);
            accr[t] = __builtin_amdgcn_mfma_f32_16x16x32_f16(awin, bi, accr[t], 0, 0, 0);
            acci[t] = __builtin_amdgcn_mfma_f32_16x16x32_f16(awr,  bi, acci[t], 0, 0, 0);
            acci[t] = __builtin_amdgcn_mfma_f32_16x16x32_f16(awi,  br, acci[t], 0, 0, 0);
        }
        awr = nwr; awi = nwi;
    }

    const int obase = t0 + 1024 * wv + 16 * n15 + 4 * lg;
    #pragma unroll
    for (int t = 0; t < 4; ++t) {
        const int tbase = t0 + 1024 * wv + 256 * t;
        if (tbase < OUTLEN) {
            const int pos = obase + 256 * t;
            *(f32x4*)(out + pos)          = accr[t];
            *(f32x4*)(out + OUTLEN + pos) = acci[t];
        }
    }
}

/* ---------- fallback (exact R3): af built in LDS, 4 blocks/CU ---------- */
__global__ __launch_bounds__(TPB, 4) void cconv_local(
    const float* __restrict__ xr, const float* __restrict__ xi,
    const float* __restrict__ wr, const float* __restrict__ wi,
    float* __restrict__ out)
{
    __shared__ half8 lx[2][XPAD];
    __shared__ half8 af[2][NCH][64];

    const int tid   = threadIdx.x;
    const int wv    = tid >> 6;
    const int lane  = tid & 63;
    const int n15   = lane & 15;
    const int lg    = lane >> 4;
    const int t0    = blockIdx.x * BT;
    const int xbase = t0 - MPAD;

    for (int i = tid; i < AFSLOT; i += TPB) {
        const int comp = i / (NCH * 64);
        const int rem  = i % (NCH * 64);
        const int c    = rem >> 6;
        const int l    = rem & 63;
        const int row  = l & 15;
        const int jb   = 32 * c + 8 * (l >> 4);
        const float* wp = comp ? wi : wr;
        half8 v;
        #pragma unroll
        for (int e = 0; e < 8; ++e) {
            const int k = jb + e - row;
            const float f = (k >= 0 && k < KTAPS) ? wp[k] : 0.0f;
            v[e] = (_Float16)f;
        }
        af[comp][c][l] = v;
    }
    stage_x(xr, xi, lx, xbase, tid);
    __syncthreads();

    f32x4 accr[4], acci[4];
    #pragma unroll
    for (int t = 0; t < 4; ++t) { accr[t] = (f32x4)0.0f; acci[t] = (f32x4)0.0f; }

    const int sT0 = 128 * wv + 2 * n15 + lg;

    #pragma unroll
    for (int c = 0; c < NCH; ++c) {
        const half8 awr  = af[0][c][lane];
        const half8 awi  = af[1][c][lane];
        const half8 awin = -awi;
        #pragma unroll
        for (int t = 0; t < 4; ++t) {
            const int Ts = swz(sT0 + 32 * t + 4 * c);
            const half8 br = lx[0][Ts];
            const half8 bi = lx[1][Ts];
            accr[t] = __builtin_amdgcn_mfma_f32_16x16x32_f16(awr,  br, accr[t], 0, 0, 0);
            accr[t] = __builtin_amdgcn_mfma_f32_16x16x32_f16(awin, bi, accr[t], 0, 0, 0);
            acci[t] = __builtin_amdgcn_mfma_f32_16x16x32_f16(awr,  bi, acci[t], 0, 0, 0);
            acci[t] = __builtin_amdgcn_mfma_f32_16x16x32_f16(awi,  br, acci[t], 0, 0, 0);
        }
    }

    const int obase = t0 + 1024 * wv + 16 * n15 + 4 * lg;
    #pragma unroll
    for (int t = 0; t < 4; ++t) {
        const int tbase = t0 + 1024 * wv + 256 * t;
        if (tbase < OUTLEN) {
            const int pos = obase + 256 * t;
            *(f32x4*)(out + pos)          = accr[t];
            *(f32x4*)(out + OUTLEN + pos) = acci[t];
        }
    }
}

extern "C" void kernel_launch(void* const* d_in, const int* in_sizes, int n_in,
                              void* d_out, int out_size, void* d_ws, size_t ws_size,
                              hipStream_t stream) {
    const float* xr = (const float*)d_in[0];
    const float* xi = (const float*)d_in[1];
    const float* wr = (const float*)d_in[2];
    const float* wi = (const float*)d_in[3];
    float* o = (float*)d_out;
    if (ws_size >= (size_t)AFSLOT * 16) {
        build_af<<<1, TPB, 0, stream>>>(wr, wi, (half8*)d_ws);
        cconv_ws<<<NBLK, TPB, 0, stream>>>(xr, xi, (const half8*)d_ws, o);
    } else {
        cconv_local<<<NBLK, TPB, 0, stream>>>(xr, xi, wr, wi, o);
    }
}

// Round 6
// 41.563 us; speedup vs baseline: 1.9055x; 1.9055x over previous
//
#include <hip/hip_runtime.h>

typedef _Float16 half8 __attribute__((ext_vector_type(8)));
typedef float    f32x4 __attribute__((ext_vector_type(4)));

#define NLEN   8388608
#define KTAPS  257
#define MPAD   256
#define OUTLEN (NLEN + MPAD)        /* 8388864 */
#define TPB    256
#define BT     2048                 /* complex outputs per block (2 tiles/wave) */
#define NBLK   ((OUTLEN + BT - 1) / BT)   /* 4097 */
#define NCH    9                    /* K chunks of 32 -> GEMM-K = 288 */
#define XELEM  (BT + 288)           /* staged elems per component: 2336 */
#define XSLOT  (XELEM / 8)          /* 292 16B slots */
#define XPAD   300                  /* + swizzle margin */
#define AFSLOT (2 * NCH * 64)       /* 1152 half8 slots = 18432 B */

__device__ __forceinline__ int swz(int t) { return t ^ ((t >> 3) & 7); }

/* ---------- staging: fp32 -> fp16 interleaved slots, swizzled ---------- */
__device__ __forceinline__ void stage_x(const float* __restrict__ xr,
                                        const float* __restrict__ xi,
                                        half8 (*lx)[XPAD], int xbase, int tid)
{
    const bool interior = (xbase >= 0) && (xbase + 8 * XSLOT <= NLEN);
    if (interior) {
        for (int T = tid; T < XSLOT; T += TPB) {
            const int g = xbase + 8 * T;
            const f32x4 a0 = *(const f32x4*)(xr + g);
            const f32x4 a1 = *(const f32x4*)(xr + g + 4);
            const f32x4 b0 = *(const f32x4*)(xi + g);
            const f32x4 b1 = *(const f32x4*)(xi + g + 4);
            half8 vr, vi;
            #pragma unroll
            for (int e = 0; e < 4; ++e) {
                vr[e]     = (_Float16)a0[e];
                vr[e + 4] = (_Float16)a1[e];
                vi[e]     = (_Float16)b0[e];
                vi[e + 4] = (_Float16)b1[e];
            }
            const int Ts = swz(T);
            lx[0][Ts] = vr;
            lx[1][Ts] = vi;
        }
    } else {
        for (int T = tid; T < XSLOT; T += TPB) {
            const int g = xbase + 8 * T;
            half8 vr, vi;
            #pragma unroll
            for (int e = 0; e < 8; ++e) {
                const int ge = g + e;
                const bool ok = (ge >= 0) && (ge < NLEN);
                vr[e] = (_Float16)(ok ? xr[ge] : 0.0f);
                vi[e] = (_Float16)(ok ? xi[ge] : 0.0f);
            }
            const int Ts = swz(T);
            lx[0][Ts] = vr;
            lx[1][Ts] = vi;
        }
    }
}

/* ---------- pre-kernel: weight-fragment table in global ws ---------- */
__global__ __launch_bounds__(TPB) void build_af(
    const float* __restrict__ wr, const float* __restrict__ wi,
    half8* __restrict__ af)
{
    for (int i = threadIdx.x; i < AFSLOT; i += TPB) {
        const int comp = i / (NCH * 64);
        const int rem  = i % (NCH * 64);
        const int c    = rem >> 6;
        const int l    = rem & 63;
        const int row  = l & 15;
        const int jb   = 32 * c + 8 * (l >> 4);
        const float* wp = comp ? wi : wr;
        half8 v;
        #pragma unroll
        for (int e = 0; e < 8; ++e) {
            const int k = jb + e - row;
            const float f = (k >= 0 && k < KTAPS) ? wp[k] : 0.0f;
            v[e] = (_Float16)f;
        }
        af[i] = v;
    }
}

/* ---------- main: 2 tiles/wave, af from ws, tiny LDS, high occupancy ---------- */
__global__ __launch_bounds__(TPB, 7) void cconv_ws2(
    const float* __restrict__ xr, const float* __restrict__ xi,
    const half8* __restrict__ af, float* __restrict__ out)
{
    __shared__ half8 lx[2][XPAD];

    const int tid   = threadIdx.x;
    const int wv    = tid >> 6;
    const int lane  = tid & 63;
    const int n15   = lane & 15;
    const int lg    = lane >> 4;
    const int t0    = blockIdx.x * BT;
    const int xbase = t0 - MPAD;

    stage_x(xr, xi, lx, xbase, tid);
    __syncthreads();

    f32x4 accr[2], acci[2];
    #pragma unroll
    for (int t = 0; t < 2; ++t) { accr[t] = (f32x4)0.0f; acci[t] = (f32x4)0.0f; }

    const int sT0 = 64 * wv + 2 * n15 + lg;    /* base 16B slot for this lane */
    const half8* afr = af + lane;              /* comp 0, chunk c at +64*c    */
    const half8* afi = af + NCH * 64 + lane;   /* comp 1                      */

    half8 awr = afr[0];
    half8 awi = afi[0];
    #pragma unroll
    for (int c = 0; c < NCH; ++c) {
        const int cn = (c + 1 < NCH) ? c + 1 : 0;   /* harmless reload on last */
        const half8 nwr = afr[cn * 64];
        const half8 nwi = afi[cn * 64];
        const half8 awin = -awi;                    /* exact fp16 sign flip */
        #pragma unroll
        for (int t = 0; t < 2; ++t) {
            const int Ts = swz(sT0 + 32 * t + 4 * c);
            const half8 br = lx[0][Ts];
            const half8 bi = lx[1][Ts];
            accr[t] = __builtin_amdgcn_mfma_f32_16x16x32_f16(awr,  br, accr[t], 0, 0, 0);
            accr[t] = __builtin_amdgcn_mfma_f32_16x16x32_f16(awin, bi, accr[t], 0, 0, 0);
            acci[t] = __builtin_amdgcn_mfma_f32_16x16x32_f16(awr,  bi, acci[t], 0, 0, 0);
            acci[t] = __builtin_amdgcn_mfma_f32_16x16x32_f16(awi,  br, acci[t], 0, 0, 0);
        }
        awr = nwr; awi = nwi;
    }

    /* epilogue: lane l holds D[4*lg + r][n15] -> 4 consecutive outputs */
    const int obase = t0 + 512 * wv + 16 * n15 + 4 * lg;
    #pragma unroll
    for (int t = 0; t < 2; ++t) {
        const int tbase = t0 + 512 * wv + 256 * t;
        if (tbase < OUTLEN) {
            const int pos = obase + 256 * t;
            *(f32x4*)(out + pos)          = accr[t];
            *(f32x4*)(out + OUTLEN + pos) = acci[t];
        }
    }
}

/* ---------- fallback (exact R3 shape): af in LDS, BT=4096 ---------- */
#define FBT    4096
#define FNBLK  ((OUTLEN + FBT - 1) / FBT)
#define FXSLOT ((FBT + 288) / 8)
#define FXPAD  556

__global__ __launch_bounds__(TPB, 4) void cconv_local(
    const float* __restrict__ xr, const float* __restrict__ xi,
    const float* __restrict__ wr, const float* __restrict__ wi,
    float* __restrict__ out)
{
    __shared__ half8 lx[2][FXPAD];
    __shared__ half8 af[2][NCH][64];

    const int tid   = threadIdx.x;
    const int wv    = tid >> 6;
    const int lane  = tid & 63;
    const int n15   = lane & 15;
    const int lg    = lane >> 4;
    const int t0    = blockIdx.x * FBT;
    const int xbase = t0 - MPAD;

    for (int i = tid; i < AFSLOT; i += TPB) {
        const int comp = i / (NCH * 64);
        const int rem  = i % (NCH * 64);
        const int c    = rem >> 6;
        const int l    = rem & 63;
        const int row  = l & 15;
        const int jb   = 32 * c + 8 * (l >> 4);
        const float* wp = comp ? wi : wr;
        half8 v;
        #pragma unroll
        for (int e = 0; e < 8; ++e) {
            const int k = jb + e - row;
            const float f = (k >= 0 && k < KTAPS) ? wp[k] : 0.0f;
            v[e] = (_Float16)f;
        }
        af[comp][c][l] = v;
    }
    {
        const bool interior = (xbase >= 0) && (xbase + 8 * FXSLOT <= NLEN);
        for (int T = tid; T < FXSLOT; T += TPB) {
            const int g = xbase + 8 * T;
            half8 vr, vi;
            if (interior || (g >= 0 && g + 8 <= NLEN)) {
                const f32x4 a0 = *(const f32x4*)(xr + g);
                const f32x4 a1 = *(const f32x4*)(xr + g + 4);
                const f32x4 b0 = *(const f32x4*)(xi + g);
                const f32x4 b1 = *(const f32x4*)(xi + g + 4);
                #pragma unroll
                for (int e = 0; e < 4; ++e) {
                    vr[e]     = (_Float16)a0[e];
                    vr[e + 4] = (_Float16)a1[e];
                    vi[e]     = (_Float16)b0[e];
                    vi[e + 4] = (_Float16)b1[e];
                }
            } else {
                #pragma unroll
                for (int e = 0; e < 8; ++e) {
                    const int ge = g + e;
                    const bool ok = (ge >= 0) && (ge < NLEN);
                    vr[e] = (_Float16)(ok ? xr[ge] : 0.0f);
                    vi[e] = (_Float16)(ok ? xi[ge] : 0.0f);
                }
            }
            const int Ts = swz(T);
            lx[0][Ts] = vr;
            lx[1][Ts] = vi;
        }
    }
    __syncthreads();

    f32x4 accr[4], acci[4];
    #pragma unroll
    for (int t = 0; t < 4; ++t) { accr[t] = (f32x4)0.0f; acci[t] = (f32x4)0.0f; }

    const int sT0 = 128 * wv + 2 * n15 + lg;

    #pragma unroll
    for (int c = 0; c < NCH; ++c) {
        const half8 awr  = af[0][c][lane];
        const half8 awi  = af[1][c][lane];
        const half8 awin = -awi;
        #pragma unroll
        for (int t = 0; t < 4; ++t) {
            const int Ts = swz(sT0 + 32 * t + 4 * c);
            const half8 br = lx[0][Ts];
            const half8 bi = lx[1][Ts];
            accr[t] = __builtin_amdgcn_mfma_f32_16x16x32_f16(awr,  br, accr[t], 0, 0, 0);
            accr[t] = __builtin_amdgcn_mfma_f32_16x16x32_f16(awin, bi, accr[t], 0, 0, 0);
            acci[t] = __builtin_amdgcn_mfma_f32_16x16x32_f16(awr,  bi, acci[t], 0, 0, 0);
            acci[t] = __builtin_amdgcn_mfma_f32_16x16x32_f16(awi,  br, acci[t], 0, 0, 0);
        }
    }

    const int obase = t0 + 1024 * wv + 16 * n15 + 4 * lg;
    #pragma unroll
    for (int t = 0; t < 4; ++t) {
        const int tbase = t0 + 1024 * wv + 256 * t;
        if (tbase < OUTLEN) {
            const int pos = obase + 256 * t;
            *(f32x4*)(out + pos)          = accr[t];
            *(f32x4*)(out + OUTLEN + pos) = acci[t];
        }
    }
}

extern "C" void kernel_launch(void* const* d_in, const int* in_sizes, int n_in,
                              void* d_out, int out_size, void* d_ws, size_t ws_size,
                              hipStream_t stream) {
    const float* xr = (const float*)d_in[0];
    const float* xi = (const float*)d_in[1];
    const float* wr = (const float*)d_in[2];
    const float* wi = (const float*)d_in[3];
    float* o = (float*)d_out;
    if (ws_size >= (size_t)AFSLOT * 16) {
        build_af<<<1, TPB, 0, stream>>>(wr, wi, (half8*)d_ws);
        cconv_ws2<<<NBLK, TPB, 0, stream>>>(xr, xi, (const half8*)d_ws, o);
    } else {
        cconv_local<<<FNBLK, TPB, 0, stream>>>(xr, xi, wr, wi, o);
    }
}